// Round 2
// baseline (220.567 us; speedup 1.0000x reference)
//
#include <hip/hip_runtime.h>
#include <hip/hip_bf16.h>

// B=4, S=4096, D=2048, H=16, dh=128, R=4, WIN=128, Cs=1024, ws=3968.
// Chunks 992..1023 are the only ones with live attention; chunks <=991 collapse
// to v[:,0,:] (forced col 0). Resize: rows 0..3965 per batch == broadcast of the
// base chunk row; rows 3966..4095 lerp between Yo rows.
//
// Structure (4 dispatches):
//   qkv_kernel  : fused f32->bf16 staging GEMM, Q (chunk-mean A), K, V
//   attn_kernel : 32x128 masked softmax-attention per (b,h)
//   o_kernel    : O-projection of 132 unique rows (f32 out)
//   resize_kernel: clamped lerp upsample -> d_out

typedef __attribute__((ext_vector_type(8))) short short8;
typedef __attribute__((ext_vector_type(4))) float f32x4;

__device__ __forceinline__ unsigned short f2bf(float f){
  unsigned int x = __float_as_uint(f);
  return (unsigned short)((x + 0x7fffu + ((x >> 16) & 1u)) >> 16);
}
__device__ __forceinline__ float bf2f(unsigned short u){
  return __uint_as_float(((unsigned int)u) << 16);
}
__device__ __forceinline__ unsigned int pk2(float lo, float hi){
  return ((unsigned int)f2bf(hi) << 16) | (unsigned int)f2bf(lo);
}
__device__ __forceinline__ short8 cvt8(float4 x, float4 y){
  union { unsigned int u[4]; short8 s; } r;
  r.u[0] = pk2(x.x, x.y); r.u[1] = pk2(x.z, x.w);
  r.u[2] = pk2(y.x, y.y); r.u[3] = pk2(y.z, y.w);
  return r.s;
}

// A-operand loaders. AMODE: 0 = bf16 rows (Ao), 1 = f32 window rows (K/V),
// 2 = mean of 4 consecutive f32 input rows (Q chunk means).
template<int AMODE>
__device__ __forceinline__ short8 load_a(const void* A, int ra, int kc){
  if constexpr (AMODE == 0){
    return *(const short8*)((const unsigned short*)A + (size_t)ra * 2048 + kc);
  } else if constexpr (AMODE == 1){
    const float* p = (const float*)A + ((size_t)(ra >> 7) * 4096 + 3968 + (ra & 127)) * 2048 + kc;
    return cvt8(*(const float4*)p, *(const float4*)(p + 4));
  } else {
    const float* p = (const float*)A + ((size_t)(ra >> 5) * 4096 + 3968 + 4 * (ra & 31)) * 2048 + kc;
    float4 x0 = *(const float4*)(p);
    float4 x1 = *(const float4*)(p + 2048);
    float4 x2 = *(const float4*)(p + 4096);
    float4 x3 = *(const float4*)(p + 6144);
    float4 y0 = *(const float4*)(p + 4);
    float4 y1 = *(const float4*)(p + 2052);
    float4 y2 = *(const float4*)(p + 4100);
    float4 y3 = *(const float4*)(p + 6148);
    float4 xm, ym;
    xm.x = 0.25f * (x0.x + x1.x + x2.x + x3.x);
    xm.y = 0.25f * (x0.y + x1.y + x2.y + x3.y);
    xm.z = 0.25f * (x0.z + x1.z + x2.z + x3.z);
    xm.w = 0.25f * (x0.w + x1.w + x2.w + x3.w);
    ym.x = 0.25f * (y0.x + y1.x + y2.x + y3.x);
    ym.y = 0.25f * (y0.y + y1.y + y2.y + y3.y);
    ym.z = 0.25f * (y0.z + y1.z + y2.z + y3.z);
    ym.w = 0.25f * (y0.w + y1.w + y2.w + y3.w);
    return cvt8(xm, ym);
  }
}

__device__ __forceinline__ short8 load_b(const float* W, int rb, int kc){
  const float* p = W + (size_t)rb * 2048 + kc;
  return cvt8(*(const float4*)p, *(const float4*)(p + 4));
}

// ---------------- GEMM: C[M,2048] = A[M,2048] @ W[2048,2048]^T ----------------
// 128x128 tile, BK=64, 4 waves (2x2 of 64x64), 16x16x32 bf16 MFMA,
// register prefetch + LDS double buffer, stride-72 pad (2-way banks, 16B aligned).
#define LDP 72

template<int AMODE, bool OUT_BF16>
__device__ __forceinline__ void gemm_body(
    const void* A, const float* W,
    unsigned short* Cb, float* Cf,
    int M, int mt, int nt,
    unsigned short* As0, unsigned short* As1,
    unsigned short* Bs0, unsigned short* Bs1)
{
  const int tid  = threadIdx.x;
  const int lane = tid & 63;
  const int wid  = tid >> 6;
  const int wr = wid >> 1, wc = wid & 1;
  const int row0 = mt * 128, n0 = nt * 128;

  const int srow = wid * 8 + (lane >> 3);   // staging row within each 32-row chunk
  const int scol = (lane & 7) * 8;          // staging col (8 bf16 = 16B)

  f32x4 acc[4][4] = {};

  // prologue: stage K-tile 0
  {
    short8 pa[4], pb[4];
    #pragma unroll
    for (int c = 0; c < 4; ++c){
      int r = c * 32 + srow;
      int ra = row0 + r; if (ra > M - 1) ra = M - 1;
      pa[c] = load_a<AMODE>(A, ra, scol);
      pb[c] = load_b(W, n0 + r, scol);
    }
    #pragma unroll
    for (int c = 0; c < 4; ++c){
      int r = c * 32 + srow;
      *(short8*)&As0[r * LDP + scol] = pa[c];
      *(short8*)&Bs0[r * LDP + scol] = pb[c];
    }
  }
  __syncthreads();

  const unsigned short* Asr = As0; const unsigned short* Bsr = Bs0;
  unsigned short* Asd = As1; unsigned short* Bsd = Bs1;

  for (int t = 0; t < 32; ++t){
    short8 na[4], nb[4];
    const bool pf = (t + 1) < 32;
    if (pf){
      const int k0 = (t + 1) * 64;
      #pragma unroll
      for (int c = 0; c < 4; ++c){
        int r = c * 32 + srow;
        int ra = row0 + r; if (ra > M - 1) ra = M - 1;
        na[c] = load_a<AMODE>(A, ra, k0 + scol);
        nb[c] = load_b(W, n0 + r, k0 + scol);
      }
    }
    #pragma unroll
    for (int ks = 0; ks < 2; ++ks){
      short8 av[4], bv[4];
      #pragma unroll
      for (int f = 0; f < 4; ++f){
        av[f] = *(const short8*)&Asr[(wr * 64 + f * 16 + (lane & 15)) * LDP + ks * 32 + (lane >> 4) * 8];
        bv[f] = *(const short8*)&Bsr[(wc * 64 + f * 16 + (lane & 15)) * LDP + ks * 32 + (lane >> 4) * 8];
      }
      #pragma unroll
      for (int fm = 0; fm < 4; ++fm)
        #pragma unroll
        for (int fn = 0; fn < 4; ++fn)
          acc[fm][fn] = __builtin_amdgcn_mfma_f32_16x16x32_bf16(av[fm], bv[fn], acc[fm][fn], 0, 0, 0);
    }
    if (pf){
      #pragma unroll
      for (int c = 0; c < 4; ++c){
        int r = c * 32 + srow;
        *(short8*)&Asd[r * LDP + scol] = na[c];
        *(short8*)&Bsd[r * LDP + scol] = nb[c];
      }
    }
    __syncthreads();
    const unsigned short* ta = Asr; Asr = Asd; Asd = (unsigned short*)ta;
    const unsigned short* tb = Bsr; Bsr = Bsd; Bsd = (unsigned short*)tb;
  }

  // epilogue: C/D layout col=lane&15, row=(lane>>4)*4+reg
  #pragma unroll
  for (int fm = 0; fm < 4; ++fm){
    #pragma unroll
    for (int fn = 0; fn < 4; ++fn){
      const int col = n0 + wc * 64 + fn * 16 + (lane & 15);
      #pragma unroll
      for (int r = 0; r < 4; ++r){
        const int row = row0 + wr * 64 + fm * 16 + (lane >> 4) * 4 + r;
        if (row < M){
          if (OUT_BF16) Cb[(size_t)row * 2048 + col] = f2bf(acc[fm][fn][r]);
          else          Cf[(size_t)row * 2048 + col] = acc[fm][fn][r];
        }
      }
    }
  }
}

__global__ __launch_bounds__(256, 2) void qkv_kernel(
    const float* __restrict__ inp,
    const float* __restrict__ Wq, const float* __restrict__ Wk, const float* __restrict__ Wv,
    unsigned short* __restrict__ Qc, unsigned short* __restrict__ Kp,
    unsigned short* __restrict__ Vp)
{
  __shared__ __align__(16) unsigned short As[2][128 * LDP];
  __shared__ __align__(16) unsigned short Bs[2][128 * LDP];
  const int gy = blockIdx.y;
  if (gy == 0)
    gemm_body<2, true>(inp, Wq, Qc, nullptr, 128, 0,      blockIdx.x, As[0], As[1], Bs[0], Bs[1]);
  else if (gy < 5)
    gemm_body<1, true>(inp, Wk, Kp, nullptr, 512, gy - 1, blockIdx.x, As[0], As[1], Bs[0], Bs[1]);
  else
    gemm_body<1, true>(inp, Wv, Vp, nullptr, 512, gy - 5, blockIdx.x, As[0], As[1], Bs[0], Bs[1]);
}

__global__ __launch_bounds__(256, 2) void o_kernel(
    const unsigned short* __restrict__ Ao, const float* __restrict__ Wo,
    float* __restrict__ Yo)
{
  __shared__ __align__(16) unsigned short As[2][128 * LDP];
  __shared__ __align__(16) unsigned short Bs[2][128 * LDP];
  gemm_body<0, false>(Ao, Wo, nullptr, Yo, 132, blockIdx.y, blockIdx.x, As[0], As[1], Bs[0], Bs[1]);
}

// ---------------- attention: chunks 992..1023 only, per (b,h) block ----------------
__global__ __launch_bounds__(256) void attn_kernel(
    const unsigned short* __restrict__ Qc, const unsigned short* __restrict__ Kp,
    const unsigned short* __restrict__ Vp, const int* __restrict__ amask,
    unsigned short* __restrict__ Ao)
{
  const int b = blockIdx.x >> 4;
  const int h = blockIdx.x & 15;
  __shared__ float Qs[32][129];
  __shared__ unsigned int Ks[128][65];
  __shared__ unsigned int Vs[128][65];
  __shared__ float Wt[32][132];
  __shared__ float msk[128];
  const int tid = threadIdx.x;

  for (int i = tid; i < 32 * 128; i += 256){
    int cq = i >> 7, d = i & 127;
    Qs[cq][d] = bf2f(Qc[(size_t)(b * 32 + cq) * 2048 + h * 128 + d]);
  }
  for (int i = tid; i < 128 * 64; i += 256){
    int j = i >> 6, du = i & 63;
    const unsigned int* kp = (const unsigned int*)(Kp + (size_t)(b * 128 + j) * 2048 + h * 128);
    const unsigned int* vp = (const unsigned int*)(Vp + (size_t)(b * 128 + j) * 2048 + h * 128);
    Ks[j][du] = kp[du];
    Vs[j][du] = vp[du];
  }
  if (tid < 128){
    msk[tid] = (amask[b * 4096 + 3968 + tid] != 0) ? 1.f : 0.f;
    // Ao base row (chunks 0..991 collapse to v[:,0,:]); mask[b,3968]==1 here
    Ao[(size_t)(b * 33) * 2048 + h * 128 + tid] = Vp[(size_t)(b * 128) * 2048 + h * 128 + tid];
  }
  __syncthreads();

  const int cq = tid >> 3, jg = tid & 7;
  const int jmax = 4 * cq + 3;   // causal: j <= 4*cq+3 for chunk 992+cq
  const float scale = 0.088388347648318447f; // 1/sqrt(128)

  float s[16];
  {
    float sacc[16];
    #pragma unroll
    for (int jj = 0; jj < 16; ++jj) sacc[jj] = 0.f;
    for (int du = 0; du < 64; ++du){
      float q0 = Qs[cq][2 * du], q1 = Qs[cq][2 * du + 1];
      #pragma unroll
      for (int jj = 0; jj < 16; ++jj){
        unsigned int u = Ks[jg * 16 + jj][du];
        sacc[jj] += q0 * __uint_as_float(u << 16) + q1 * __uint_as_float(u & 0xffff0000u);
      }
    }
    #pragma unroll
    for (int jj = 0; jj < 16; ++jj){
      int j = jg * 16 + jj;
      bool ok = (j <= jmax) && (msk[j] > 0.5f);
      s[jj] = ok ? sacc[jj] * scale : -1e9f;
    }
  }
  float m = s[0];
  #pragma unroll
  for (int jj = 1; jj < 16; ++jj) m = fmaxf(m, s[jj]);
  #pragma unroll
  for (int off = 1; off < 8; off <<= 1) m = fmaxf(m, __shfl_xor(m, off, 8));
  float sum = 0.f;
  #pragma unroll
  for (int jj = 0; jj < 16; ++jj){ s[jj] = expf(s[jj] - m); sum += s[jj]; }
  #pragma unroll
  for (int off = 1; off < 8; off <<= 1) sum += __shfl_xor(sum, off, 8);
  const float inv = 1.f / sum;
  #pragma unroll
  for (int jj = 0; jj < 16; ++jj) Wt[cq][jg * 16 + jj] = s[jj] * inv;
  __syncthreads();

  const int dg = tid & 7;
  float o[16];
  #pragma unroll
  for (int e = 0; e < 16; ++e) o[e] = 0.f;
  for (int j = 0; j < 128; ++j){
    float w = Wt[cq][j];
    #pragma unroll
    for (int du = 0; du < 8; ++du){
      unsigned int u = Vs[j][dg * 8 + du];
      o[2 * du]     += w * __uint_as_float(u << 16);
      o[2 * du + 1] += w * __uint_as_float(u & 0xffff0000u);
    }
  }
  unsigned short* dst = Ao + (size_t)(b * 33 + 1 + cq) * 2048 + h * 128 + dg * 16;
  #pragma unroll
  for (int e = 0; e < 16; ++e) dst[e] = f2bf(o[e]);
}

// ---------------- resize: linear upsample Cs=1024 -> S=4096 (clamped lerp) ----------------
__global__ __launch_bounds__(256) void resize_kernel(
    const float* __restrict__ Yo, float* __restrict__ out)
{
  const int rowid = blockIdx.x;       // b*4096 + i
  const int b = rowid >> 12;
  const int i = rowid & 4095;
  float c  = i * 0.25f - 0.375f;
  float fl = floorf(c);
  int   j0 = (int)fl;
  float f  = c - fl;
  int   j1 = j0 + 1;
  j0 = max(0, min(j0, 1023));
  j1 = max(0, min(j1, 1023));
  const float* r0 = Yo + (size_t)(b * 33 + (j0 <= 991 ? 0 : j0 - 991)) * 2048;
  const float* r1 = Yo + (size_t)(b * 33 + (j1 <= 991 ? 0 : j1 - 991)) * 2048;
  float* op = out + (size_t)rowid * 2048;
  const int t = threadIdx.x;
  #pragma unroll
  for (int q = 0; q < 2; ++q){
    int d = q * 1024 + t * 4;
    float4 a  = *(const float4*)(r0 + d);
    float4 bb = *(const float4*)(r1 + d);
    float4 o;
    o.x = a.x + f * (bb.x - a.x);
    o.y = a.y + f * (bb.y - a.y);
    o.z = a.z + f * (bb.z - a.z);
    o.w = a.w + f * (bb.w - a.w);
    *(float4*)(op + d) = o;
  }
}

extern "C" void kernel_launch(void* const* d_in, const int* in_sizes, int n_in,
                              void* d_out, int out_size, void* d_ws, size_t ws_size,
                              hipStream_t stream)
{
  const float* inp   = (const float*)d_in[0];
  const int*   amask = (const int*)d_in[1];
  const float* Wq = (const float*)d_in[2];
  const float* Wk = (const float*)d_in[3];
  const float* Wv = (const float*)d_in[4];
  const float* Wo = (const float*)d_in[5];
  float* out = (float*)d_out;

  char* ws = (char*)d_ws;
  unsigned short* Qc = (unsigned short*)(ws);            // 128 x 2048 bf16 (rows b*32+c)
  unsigned short* Kp = (unsigned short*)(ws + 524288);   // 512 x 2048 bf16 (rows b*128+j)
  unsigned short* Vp = (unsigned short*)(ws + 2621440);  // 512 x 2048 bf16
  unsigned short* Ao = (unsigned short*)(ws + 4718592);  // 132 x 2048 bf16 (rows b*33+0..32)
  float*          Yo = (float*)(ws + 5259264);           // 132 x 2048 f32

  qkv_kernel<<<dim3(16, 9), 256, 0, stream>>>(inp, Wq, Wk, Wv, Qc, Kp, Vp);
  attn_kernel<<<64, 256, 0, stream>>>(Qc, Kp, Vp, amask, Ao);
  o_kernel<<<dim3(16, 2), 256, 0, stream>>>(Ao, Wo, Yo);
  resize_kernel<<<16384, 256, 0, stream>>>(Yo, out);
}

// Round 3
// 156.594 us; speedup vs baseline: 1.4085x; 1.4085x over previous
//
#include <hip/hip_runtime.h>
#include <hip/hip_bf16.h>

// B=4, S=4096, D=2048, H=16, dh=128, R=4, WIN=128, Cs=1024, ws=3968.
// Chunks 992..1023 are the only ones with live attention; chunks <=991 collapse
// to v[:,0,:]. Resize rows 0..3965 per batch broadcast the base chunk row.
//
// Structure (5 dispatches):
//   memset      : zero f32 accumulation buffers (Qc,Kp,Vp,Yo)
//   qkv_kernel  : split-K (8-way) fused f32->bf16 staging GEMM, atomic f32 out
//   attn_kernel : 32x128 masked softmax-attention per (b,h)
//   o_kernel    : split-K O-projection of 132 unique rows, atomic f32 out
//   resize_kernel: clamped lerp upsample -> d_out

typedef __attribute__((ext_vector_type(8))) short short8;
typedef __attribute__((ext_vector_type(4))) float f32x4;

#define KSPLIT 8      // 2048 / 8 = 256 K-cols per block = 4 BK=64 steps
#define LDP 72        // LDS row stride in bf16 (144 B: 16B-aligned, low conflict)

__device__ __forceinline__ unsigned short f2bf(float f){
  unsigned int x = __float_as_uint(f);
  return (unsigned short)((x + 0x7fffu + ((x >> 16) & 1u)) >> 16);
}
__device__ __forceinline__ unsigned int pk2(float lo, float hi){
  return ((unsigned int)f2bf(hi) << 16) | (unsigned int)f2bf(lo);
}
__device__ __forceinline__ short8 cvt8(float4 x, float4 y){
  union { unsigned int u[4]; short8 s; } r;
  r.u[0] = pk2(x.x, x.y); r.u[1] = pk2(x.z, x.w);
  r.u[2] = pk2(y.x, y.y); r.u[3] = pk2(y.z, y.w);
  return r.s;
}

// A-operand loaders. AMODE: 0 = bf16 rows (Ao), 1 = f32 window rows (K/V),
// 2 = mean of 4 consecutive f32 input rows (Q chunk means).
template<int AMODE>
__device__ __forceinline__ short8 load_a(const void* A, int ra, int kc){
  if constexpr (AMODE == 0){
    return *(const short8*)((const unsigned short*)A + (size_t)ra * 2048 + kc);
  } else if constexpr (AMODE == 1){
    const float* p = (const float*)A + ((size_t)(ra >> 7) * 4096 + 3968 + (ra & 127)) * 2048 + kc;
    return cvt8(*(const float4*)p, *(const float4*)(p + 4));
  } else {
    const float* p = (const float*)A + ((size_t)(ra >> 5) * 4096 + 3968 + 4 * (ra & 31)) * 2048 + kc;
    float4 x0 = *(const float4*)(p);
    float4 x1 = *(const float4*)(p + 2048);
    float4 x2 = *(const float4*)(p + 4096);
    float4 x3 = *(const float4*)(p + 6144);
    float4 y0 = *(const float4*)(p + 4);
    float4 y1 = *(const float4*)(p + 2052);
    float4 y2 = *(const float4*)(p + 4100);
    float4 y3 = *(const float4*)(p + 6148);
    float4 xm, ym;
    xm.x = 0.25f * (x0.x + x1.x + x2.x + x3.x);
    xm.y = 0.25f * (x0.y + x1.y + x2.y + x3.y);
    xm.z = 0.25f * (x0.z + x1.z + x2.z + x3.z);
    xm.w = 0.25f * (x0.w + x1.w + x2.w + x3.w);
    ym.x = 0.25f * (y0.x + y1.x + y2.x + y3.x);
    ym.y = 0.25f * (y0.y + y1.y + y2.y + y3.y);
    ym.z = 0.25f * (y0.z + y1.z + y2.z + y3.z);
    ym.w = 0.25f * (y0.w + y1.w + y2.w + y3.w);
    return cvt8(xm, ym);
  }
}

__device__ __forceinline__ short8 load_b(const float* W, int rb, int kc){
  const float* p = W + (size_t)rb * 2048 + kc;
  return cvt8(*(const float4*)p, *(const float4*)(p + 4));
}

// ---- split-K GEMM slice: C[row0..+127, n0..+127] += A[.,kb..kb+255] @ W^T ----
// 128x128 tile, BK=64, 4 waves (2x2 of 64x64), 16x16x32 bf16 MFMA,
// register prefetch + LDS double buffer, atomic f32 epilogue.
template<int AMODE>
__device__ __forceinline__ void gemm_body(
    const void* A, const float* W, float* C,
    int M, int mt, int nt, int ksp,
    unsigned short* As0, unsigned short* As1,
    unsigned short* Bs0, unsigned short* Bs1)
{
  const int tid  = threadIdx.x;
  const int lane = tid & 63;
  const int wid  = tid >> 6;
  const int wr = wid >> 1, wc = wid & 1;
  const int row0 = mt * 128, n0 = nt * 128;
  const int kbase = ksp * 256;

  const int srow = wid * 8 + (lane >> 3);   // staging row within each 32-row chunk
  const int scol = (lane & 7) * 8;          // staging col (8 bf16 = 16B)

  f32x4 acc[4][4] = {};

  // prologue: stage K-tile 0
  {
    short8 pa[4], pb[4];
    #pragma unroll
    for (int c = 0; c < 4; ++c){
      int r = c * 32 + srow;
      int ra = row0 + r; if (ra > M - 1) ra = M - 1;
      pa[c] = load_a<AMODE>(A, ra, kbase + scol);
      pb[c] = load_b(W, n0 + r, kbase + scol);
    }
    #pragma unroll
    for (int c = 0; c < 4; ++c){
      int r = c * 32 + srow;
      *(short8*)&As0[r * LDP + scol] = pa[c];
      *(short8*)&Bs0[r * LDP + scol] = pb[c];
    }
  }
  __syncthreads();

  const unsigned short* Asr = As0; const unsigned short* Bsr = Bs0;
  unsigned short* Asd = As1; unsigned short* Bsd = Bs1;

  #pragma unroll
  for (int t = 0; t < 4; ++t){
    short8 na[4], nb[4];
    const bool pf = (t + 1) < 4;
    if (pf){
      const int k0 = kbase + (t + 1) * 64;
      #pragma unroll
      for (int c = 0; c < 4; ++c){
        int r = c * 32 + srow;
        int ra = row0 + r; if (ra > M - 1) ra = M - 1;
        na[c] = load_a<AMODE>(A, ra, k0 + scol);
        nb[c] = load_b(W, n0 + r, k0 + scol);
      }
    }
    #pragma unroll
    for (int ks = 0; ks < 2; ++ks){
      short8 av[4], bv[4];
      #pragma unroll
      for (int f = 0; f < 4; ++f){
        av[f] = *(const short8*)&Asr[(wr * 64 + f * 16 + (lane & 15)) * LDP + ks * 32 + (lane >> 4) * 8];
        bv[f] = *(const short8*)&Bsr[(wc * 64 + f * 16 + (lane & 15)) * LDP + ks * 32 + (lane >> 4) * 8];
      }
      #pragma unroll
      for (int fm = 0; fm < 4; ++fm)
        #pragma unroll
        for (int fn = 0; fn < 4; ++fn)
          acc[fm][fn] = __builtin_amdgcn_mfma_f32_16x16x32_bf16(av[fm], bv[fn], acc[fm][fn], 0, 0, 0);
    }
    if (pf){
      #pragma unroll
      for (int c = 0; c < 4; ++c){
        int r = c * 32 + srow;
        *(short8*)&Asd[r * LDP + scol] = na[c];
        *(short8*)&Bsd[r * LDP + scol] = nb[c];
      }
    }
    __syncthreads();
    const unsigned short* ta = Asr; Asr = Asd; Asd = (unsigned short*)ta;
    const unsigned short* tb = Bsr; Bsr = Bsd; Bsd = (unsigned short*)tb;
  }

  // epilogue: C/D layout col=lane&15, row=(lane>>4)*4+reg; accumulate via atomics
  #pragma unroll
  for (int fm = 0; fm < 4; ++fm){
    #pragma unroll
    for (int fn = 0; fn < 4; ++fn){
      const int col = n0 + wc * 64 + fn * 16 + (lane & 15);
      #pragma unroll
      for (int r = 0; r < 4; ++r){
        const int row = row0 + wr * 64 + fm * 16 + (lane >> 4) * 4 + r;
        if (row < M)
          atomicAdd(&C[(size_t)row * 2048 + col], acc[fm][fn][r]);
      }
    }
  }
}

__global__ __launch_bounds__(256, 2) void qkv_kernel(
    const float* __restrict__ inp,
    const float* __restrict__ Wq, const float* __restrict__ Wk, const float* __restrict__ Wv,
    float* __restrict__ Qc, float* __restrict__ Kp, float* __restrict__ Vp)
{
  __shared__ __align__(16) unsigned short As[2][128 * LDP];
  __shared__ __align__(16) unsigned short Bs[2][128 * LDP];
  const int gy = blockIdx.y, ksp = blockIdx.z;
  if (gy == 0)
    gemm_body<2>(inp, Wq, Qc, 128, 0,      blockIdx.x, ksp, As[0], As[1], Bs[0], Bs[1]);
  else if (gy < 5)
    gemm_body<1>(inp, Wk, Kp, 512, gy - 1, blockIdx.x, ksp, As[0], As[1], Bs[0], Bs[1]);
  else
    gemm_body<1>(inp, Wv, Vp, 512, gy - 5, blockIdx.x, ksp, As[0], As[1], Bs[0], Bs[1]);
}

__global__ __launch_bounds__(256, 2) void o_kernel(
    const unsigned short* __restrict__ Ao, const float* __restrict__ Wo,
    float* __restrict__ Yo)
{
  __shared__ __align__(16) unsigned short As[2][128 * LDP];
  __shared__ __align__(16) unsigned short Bs[2][128 * LDP];
  gemm_body<0>(Ao, Wo, Yo, 132, blockIdx.y, blockIdx.x, blockIdx.z, As[0], As[1], Bs[0], Bs[1]);
}

// ---------------- attention: chunks 992..1023 only, per (b,h) block ----------------
__global__ __launch_bounds__(256) void attn_kernel(
    const float* __restrict__ Qc, const float* __restrict__ Kp,
    const float* __restrict__ Vp, const int* __restrict__ amask,
    unsigned short* __restrict__ Ao)
{
  const int b = blockIdx.x >> 4;
  const int h = blockIdx.x & 15;
  __shared__ float Qs[32][129];
  __shared__ unsigned int Ks[128][65];
  __shared__ unsigned int Vs[128][65];
  __shared__ float Wt[32][132];
  __shared__ float msk[128];
  const int tid = threadIdx.x;

  for (int i = tid; i < 32 * 128; i += 256){
    int cq = i >> 7, d = i & 127;
    Qs[cq][d] = Qc[(size_t)(b * 32 + cq) * 2048 + h * 128 + d];
  }
  for (int i = tid; i < 128 * 64; i += 256){
    int j = i >> 6, du = i & 63;
    const float* kp = Kp + (size_t)(b * 128 + j) * 2048 + h * 128 + du * 2;
    const float* vp = Vp + (size_t)(b * 128 + j) * 2048 + h * 128 + du * 2;
    float2 kk = *(const float2*)kp;
    float2 vv = *(const float2*)vp;
    Ks[j][du] = pk2(kk.x, kk.y);
    Vs[j][du] = pk2(vv.x, vv.y);
  }
  if (tid < 128){
    msk[tid] = (amask[b * 4096 + 3968 + tid] != 0) ? 1.f : 0.f;
    // Ao base row (chunks 0..991 collapse to v[:,0,:]); mask[b,3968]==1 here
    Ao[(size_t)(b * 33) * 2048 + h * 128 + tid] =
        f2bf(Vp[(size_t)(b * 128) * 2048 + h * 128 + tid]);
  }
  __syncthreads();

  const int cq = tid >> 3, jg = tid & 7;
  const int jmax = 4 * cq + 3;   // causal: j <= 4*cq+3 for chunk 992+cq
  const float scale = 0.088388347648318447f; // 1/sqrt(128)

  float s[16];
  {
    float sacc[16];
    #pragma unroll
    for (int jj = 0; jj < 16; ++jj) sacc[jj] = 0.f;
    for (int du = 0; du < 64; ++du){
      float q0 = Qs[cq][2 * du], q1 = Qs[cq][2 * du + 1];
      #pragma unroll
      for (int jj = 0; jj < 16; ++jj){
        unsigned int u = Ks[jg * 16 + jj][du];
        sacc[jj] += q0 * __uint_as_float(u << 16) + q1 * __uint_as_float(u & 0xffff0000u);
      }
    }
    #pragma unroll
    for (int jj = 0; jj < 16; ++jj){
      int j = jg * 16 + jj;
      bool ok = (j <= jmax) && (msk[j] > 0.5f);
      s[jj] = ok ? sacc[jj] * scale : -1e9f;
    }
  }
  float m = s[0];
  #pragma unroll
  for (int jj = 1; jj < 16; ++jj) m = fmaxf(m, s[jj]);
  #pragma unroll
  for (int off = 1; off < 8; off <<= 1) m = fmaxf(m, __shfl_xor(m, off, 8));
  float sum = 0.f;
  #pragma unroll
  for (int jj = 0; jj < 16; ++jj){ s[jj] = expf(s[jj] - m); sum += s[jj]; }
  #pragma unroll
  for (int off = 1; off < 8; off <<= 1) sum += __shfl_xor(sum, off, 8);
  const float inv = 1.f / sum;
  #pragma unroll
  for (int jj = 0; jj < 16; ++jj) Wt[cq][jg * 16 + jj] = s[jj] * inv;
  __syncthreads();

  const int dg = tid & 7;
  float o[16];
  #pragma unroll
  for (int e = 0; e < 16; ++e) o[e] = 0.f;
  for (int j = 0; j < 128; ++j){
    float w = Wt[cq][j];
    #pragma unroll
    for (int du = 0; du < 8; ++du){
      unsigned int u = Vs[j][dg * 8 + du];
      o[2 * du]     += w * __uint_as_float(u << 16);
      o[2 * du + 1] += w * __uint_as_float(u & 0xffff0000u);
    }
  }
  unsigned short* dst = Ao + (size_t)(b * 33 + 1 + cq) * 2048 + h * 128 + dg * 16;
  #pragma unroll
  for (int e = 0; e < 16; ++e) dst[e] = f2bf(o[e]);
}

// ---------------- resize: linear upsample Cs=1024 -> S=4096 (clamped lerp) ----------------
__global__ __launch_bounds__(256) void resize_kernel(
    const float* __restrict__ Yo, float* __restrict__ out)
{
  const int rowid = blockIdx.x;       // b*4096 + i
  const int b = rowid >> 12;
  const int i = rowid & 4095;
  float c  = i * 0.25f - 0.375f;
  float fl = floorf(c);
  int   j0 = (int)fl;
  float f  = c - fl;
  int   j1 = j0 + 1;
  j0 = max(0, min(j0, 1023));
  j1 = max(0, min(j1, 1023));
  const float* r0 = Yo + (size_t)(b * 33 + (j0 <= 991 ? 0 : j0 - 991)) * 2048;
  const float* r1 = Yo + (size_t)(b * 33 + (j1 <= 991 ? 0 : j1 - 991)) * 2048;
  float* op = out + (size_t)rowid * 2048;
  const int t = threadIdx.x;
  #pragma unroll
  for (int q = 0; q < 2; ++q){
    int d = q * 1024 + t * 4;
    float4 a  = *(const float4*)(r0 + d);
    float4 bb = *(const float4*)(r1 + d);
    float4 o;
    o.x = a.x + f * (bb.x - a.x);
    o.y = a.y + f * (bb.y - a.y);
    o.z = a.z + f * (bb.z - a.z);
    o.w = a.w + f * (bb.w - a.w);
    *(float4*)(op + d) = o;
  }
}

extern "C" void kernel_launch(void* const* d_in, const int* in_sizes, int n_in,
                              void* d_out, int out_size, void* d_ws, size_t ws_size,
                              hipStream_t stream)
{
  const float* inp   = (const float*)d_in[0];
  const int*   amask = (const int*)d_in[1];
  const float* Wq = (const float*)d_in[2];
  const float* Wk = (const float*)d_in[3];
  const float* Wv = (const float*)d_in[4];
  const float* Wo = (const float*)d_in[5];
  float* out = (float*)d_out;

  char* ws = (char*)d_ws;
  float*          Qc = (float*)(ws);                       // 128 x 2048 f32 (rows b*32+c)
  float*          Kp = (float*)(ws + 1048576);             // 512 x 2048 f32 (rows b*128+j)
  float*          Vp = (float*)(ws + 5242880);             // 512 x 2048 f32
  float*          Yo = (float*)(ws + 9437184);             // 132 x 2048 f32 (rows b*33+0..32)
  unsigned short* Ao = (unsigned short*)(ws + 10518528);   // 132 x 2048 bf16

  // zero the atomic-accumulation targets (Qc..Yo contiguous)
  hipMemsetAsync(ws, 0, 10518528, stream);

  qkv_kernel<<<dim3(16, 9, KSPLIT), 256, 0, stream>>>(inp, Wq, Wk, Wv, Qc, Kp, Vp);
  attn_kernel<<<64, 256, 0, stream>>>(Qc, Kp, Vp, amask, Ao);
  o_kernel<<<dim3(16, 2, KSPLIT), 256, 0, stream>>>(Ao, Wo, Yo);
  resize_kernel<<<16384, 256, 0, stream>>>(Yo, out);
}